// Round 8
// baseline (429.764 us; speedup 1.0000x reference)
//
#include <hip/hip_runtime.h>

typedef __attribute__((ext_vector_type(8))) __bf16 bf16x8;
typedef __attribute__((ext_vector_type(4))) float f32x4;
typedef __attribute__((ext_vector_type(4))) unsigned short u16x4;
typedef unsigned short u16;

// ws layout (u16 element offsets)
#define OFF_QB   0L            // query bf16   [8192][512]
#define OFF_KB   4194304L      // key bf16
#define OFF_VB   8388608L      // value bf16
#define OFF_WQ   12582912L     // Wq bf16 [512][512]
#define OFF_WK   12845056L
#define OFF_WV   13107200L
#define OFF_WO   13369344L
#define OFF_QS   13631488L     // Q*(log2e/8)  [BH][2048][64] bf16
#define OFF_KS   17825792L     // K    [BH][2048][64]
#define OFF_VT   22020096L     // V^T  [BH][64][2048]
#define OFF_CTX  26214400L     // ctx  [8192][512]
#define WS_NEEDED_U16 30408704L

static __device__ __forceinline__ u16 f2bf(float f) {
  union { float f; unsigned u; } v; v.f = f;
  unsigned r = v.u + 0x7FFFu + ((v.u >> 16) & 1u);
  return (u16)(r >> 16);
}

static __device__ __forceinline__ f32x4 mfma16(bf16x8 a, bf16x8 b, f32x4 c) {
  return __builtin_amdgcn_mfma_f32_16x16x32_bf16(a, b, c, 0, 0, 0);
}

// ---- convert fp32 inputs/weights to bf16 in ws ----
__global__ __launch_bounds__(256) void k_cvt(
    const float* __restrict__ q, const float* __restrict__ k, const float* __restrict__ v,
    const float* __restrict__ wq, const float* __restrict__ wk, const float* __restrict__ wv,
    const float* __restrict__ wo, u16* __restrict__ ws0) {
  long i = ((long)blockIdx.x * 256 + threadIdx.x) * 4;
  const float* src; u16* dst; long off;
  if (i < 12582912L) {
    int which = (int)(i >> 22); off = i & 4194303L;
    src = which == 0 ? q : which == 1 ? k : v;
    dst = ws0 + (long)which * 4194304L;
  } else {
    long j = i - 12582912L;
    int which = (int)(j >> 18); off = j & 262143L;
    src = which == 0 ? wq : which == 1 ? wk : which == 2 ? wv : wo;
    dst = ws0 + 12582912L + (long)which * 262144L;
  }
  float4 f = *(const float4*)(src + off);
  u16x4 o; o.x = f2bf(f.x); o.y = f2bf(f.y); o.z = f2bf(f.z); o.w = f2bf(f.w);
  *(u16x4*)(dst + off) = o;
}

// ---- Q/K projections: C = X @ W^T + b, stored [BH][S][D]; Q scaled by log2e/8 ----
__global__ __launch_bounds__(256) void k_proj_qk(
    const u16* __restrict__ ws0, const float* __restrict__ bq, const float* __restrict__ bk) {
  const int wv  = threadIdx.x >> 6;
  const int lane = threadIdx.x & 63;
  const int r16 = lane & 15, g8 = (lane >> 4) * 8, rq = (lane >> 4) * 4;
  const int t0 = blockIdx.x * 64 + wv * 16;
  const int e0 = blockIdx.y * 64;
  const int z  = blockIdx.z;                 // 0=Q 1=K
  const u16* xb = ws0 + (z == 0 ? OFF_QB : OFF_KB);
  const u16* wb = ws0 + (z == 0 ? OFF_WQ : OFF_WK);
  const float* bias = (z == 0) ? bq : bk;
  u16* dst = (u16*)ws0 + (z == 0 ? OFF_QS : OFF_KS);
  const float scl = (z == 0) ? 0.125f * 1.4426950408889634f : 1.0f;

  f32x4 acc[4] = {};
  const u16* arow = xb + (long)(t0 + r16) * 512 + g8;
  for (int f = 0; f < 512; f += 32) {
    bf16x8 a = *(const bf16x8*)(arow + f);
#pragma unroll
    for (int nt = 0; nt < 4; ++nt) {
      bf16x8 bfr = *(const bf16x8*)(wb + (long)(e0 + nt * 16 + r16) * 512 + f + g8);
      acc[nt] = mfma16(a, bfr, acc[nt]);
    }
  }
#pragma unroll
  for (int nt = 0; nt < 4; ++nt) {
    int e = e0 + nt * 16 + r16;
    float bb = bias[e];
    int h = e >> 6, d = e & 63;
#pragma unroll
    for (int r = 0; r < 4; ++r) {
      int t = t0 + rq + r;
      int b = t >> 11, s = t & 2047;
      float val = (acc[nt][r] + bb) * scl;
      dst[((long)(b * 8 + h) * 2048 + s) * 64 + d] = f2bf(val);
    }
  }
}

// ---- V projection, transposed: C = Wv @ X^T (+bv per row), stored [BH][D][S] ----
__global__ __launch_bounds__(256) void k_proj_v(
    const u16* __restrict__ ws0, const float* __restrict__ bv) {
  const int wv  = threadIdx.x >> 6;
  const int lane = threadIdx.x & 63;
  const int r16 = lane & 15, g8 = (lane >> 4) * 8, rq = (lane >> 4) * 4;
  const int e0 = blockIdx.x * 64 + wv * 16;   // output channel rows
  const int t0 = blockIdx.y * 64;             // token cols
  const u16* xb = ws0 + OFF_VB;
  const u16* wb = ws0 + OFF_WV;
  u16* vt = (u16*)ws0 + OFF_VT;

  f32x4 acc[4] = {};
  const u16* arow = wb + (long)(e0 + r16) * 512 + g8;
  for (int f = 0; f < 512; f += 32) {
    bf16x8 a = *(const bf16x8*)(arow + f);
#pragma unroll
    for (int nt = 0; nt < 4; ++nt) {
      bf16x8 bfr = *(const bf16x8*)(xb + (long)(t0 + nt * 16 + r16) * 512 + f + g8);
      acc[nt] = mfma16(a, bfr, acc[nt]);
    }
  }
#pragma unroll
  for (int r = 0; r < 4; ++r) {
    int e = e0 + rq + r;
    float bb = bv[e];
    int h = e >> 6, d = e & 63;
#pragma unroll
    for (int nt = 0; nt < 4; ++nt) {
      int t = t0 + nt * 16 + r16;
      int b = t >> 11, s = t & 2047;
      vt[((long)((b * 8 + h) * 64 + d)) * 2048 + s] = f2bf(acc[nt][r] + bb);
    }
  }
}

// ---- fused attention v4b: 4-wave block per balanced q-pair, k-split waves ----
// Scores in log2 domain (log2e/8 folded into Q). 2 passes, no max.
// P1: partial l per wave (tiles ti = w mod 4) -> LDS reduce (barrier A).
// P2: normalized p = exp2(s + bias*L2E + cc) -> attn write + partial PV.
// cacc cross-wave SUM (p already normalized -> NO extra 1/l!) -> ctx.
__global__ __launch_bounds__(256) void k_attn(
    const u16* __restrict__ ws0, const float* __restrict__ pos_bias,
    const int* __restrict__ mask, float* __restrict__ attn_out, u16* __restrict__ ctx) {
  __shared__ __align__(16) u16 p_st[4][16][40];
  __shared__ float red_l[4][16];
  __shared__ __align__(16) float cred[4][16][68];

  const int tid = threadIdx.x;
  const int w = tid >> 6, lane = tid & 63;
  const int r16 = lane & 15, g = lane >> 4;
  const int g8 = g * 8, rq = g * 4;
  const int bh = blockIdx.y;                  // 0..31
  const int b = bh >> 3, h = bh & 7;
  const int pair = blockIdx.x;                // 0..63
  const u16* Qs = ws0 + OFF_QS + (long)bh * (2048 * 64);
  const u16* Ks = ws0 + OFF_KS + (long)bh * (2048 * 64);
  const u16* VT = ws0 + OFF_VT + (long)bh * (64 * 2048);
  const int* maskb = mask + b * 2048;
  const float NEG = -1e30f;
  const float L2E = 1.4426950408889634f;
  bool dg[4];                                  // causal kill on diagonal tile
#pragma unroll
  for (int r = 0; r < 4; ++r) dg[r] = (r16 > rq + r);

  for (int qsel = 0; qsel < 2; ++qsel) {
    const int qb = qsel ? (127 - pair) : pair;
    const int q0 = qb * 16;
    const int ntiles = qb + 1;
    const int kend = ntiles * 16;
    bf16x8 qf0 = *(const bf16x8*)(Qs + (long)(q0 + r16) * 64 + g8);
    bf16x8 qf1 = *(const bf16x8*)(Qs + (long)(q0 + r16) * 64 + 32 + g8);
    const float* brow = pos_bias + ((long)h * 2048 + q0 + rq) * 2048;

    // ---------- P1: partial l over this wave's tiles ----------
    float l[4] = {0.f, 0.f, 0.f, 0.f};
    for (int ti = w; ti < ntiles; ti += 4) {
      int kcol = ti * 16 + r16;
      bf16x8 kf0 = *(const bf16x8*)(Ks + (long)kcol * 64 + g8);
      bf16x8 kf1 = *(const bf16x8*)(Ks + (long)kcol * 64 + 32 + g8);
      f32x4 s = {};
      s = mfma16(qf0, kf0, s);
      s = mfma16(qf1, kf1, s);
      bool mz = (maskb[kcol] == 0);
      bool edge = (ti == qb);                  // wave-uniform
#pragma unroll
      for (int r = 0; r < 4; ++r) {
        float sv = fmaf(brow[(long)r * 2048 + kcol], L2E, s[r]);
        if (mz || (edge && dg[r])) sv = NEG;
        l[r] += exp2f(sv);
      }
    }
#pragma unroll
    for (int r = 0; r < 4; ++r)
#pragma unroll
      for (int off = 1; off < 16; off <<= 1) l[r] += __shfl_xor(l[r], off);
    if (r16 == 0) {
#pragma unroll
      for (int r = 0; r < 4; ++r) red_l[w][rq + r] = l[r];
    }
    __syncthreads();   // A
    float cc[4];
#pragma unroll
    for (int r = 0; r < 4; ++r) {
      float ls = red_l[0][rq + r] + red_l[1][rq + r] + red_l[2][rq + r] + red_l[3][rq + r];
      cc[r] = -__log2f(ls);
    }

    // ---------- P2: normalized p -> attn write + partial PV ----------
    f32x4 cacc[4] = {};
    float* arow = attn_out + ((long)bh * 2048 + q0) * 2048;
    for (int ta = w; ta < ntiles; ta += 8) {
      const int tb = ta + 4;
      const bool have1 = (tb < ntiles);
      float p0[4], p1[4];
      {
        int kcol = ta * 16 + r16;
        bf16x8 kf0 = *(const bf16x8*)(Ks + (long)kcol * 64 + g8);
        bf16x8 kf1 = *(const bf16x8*)(Ks + (long)kcol * 64 + 32 + g8);
        f32x4 s = {};
        s = mfma16(qf0, kf0, s);
        s = mfma16(qf1, kf1, s);
        bool mz = (maskb[kcol] == 0);
        bool edge = (ta == qb);
#pragma unroll
        for (int r = 0; r < 4; ++r) {
          float sv = fmaf(brow[(long)r * 2048 + kcol], L2E, s[r]);
          if (mz || (edge && dg[r])) sv = NEG;
          float pv = exp2f(sv + cc[r]);
          p0[r] = pv;
          __builtin_nontemporal_store(pv, &arow[(long)(rq + r) * 2048 + kcol]);
        }
      }
      if (have1) {
        int kcol = tb * 16 + r16;
        bf16x8 kf0 = *(const bf16x8*)(Ks + (long)kcol * 64 + g8);
        bf16x8 kf1 = *(const bf16x8*)(Ks + (long)kcol * 64 + 32 + g8);
        f32x4 s = {};
        s = mfma16(qf0, kf0, s);
        s = mfma16(qf1, kf1, s);
        bool mz = (maskb[kcol] == 0);
        bool edge = (tb == qb);
#pragma unroll
        for (int r = 0; r < 4; ++r) {
          float sv = fmaf(brow[(long)r * 2048 + kcol], L2E, s[r]);
          if (mz || (edge && dg[r])) sv = NEG;
          float pv = exp2f(sv + cc[r]);
          p1[r] = pv;
          __builtin_nontemporal_store(pv, &arow[(long)(rq + r) * 2048 + kcol]);
        }
      } else {
#pragma unroll
        for (int r = 0; r < 4; ++r) p1[r] = 0.0f;
      }
#pragma unroll
      for (int r = 0; r < 4; ++r) {
        p_st[w][rq + r][r16]      = f2bf(p0[r]);
        p_st[w][rq + r][16 + r16] = f2bf(p1[r]);
      }
      int tsel = (g < 2) ? ta : (have1 ? tb : ta);
      const u16* vcol = VT + tsel * 16 + (g8 & 15);
      bf16x8 pa = *(const bf16x8*)&p_st[w][r16][g8];
#pragma unroll
      for (int dt = 0; dt < 4; ++dt) {
        bf16x8 vf = *(const bf16x8*)(vcol + (long)(dt * 16 + r16) * 2048);
        cacc[dt] = mfma16(pa, vf, cacc[dt]);
      }
    }
    // stash partial cacc
#pragma unroll
    for (int dt = 0; dt < 4; ++dt)
#pragma unroll
      for (int r = 0; r < 4; ++r)
        cred[w][rq + r][dt * 16 + r16] = cacc[dt][r];

    // zero tail [kend, 2048), rows split across waves
    for (int rr = w; rr < 16; rr += 4) {
      float* rowp = arow + (long)rr * 2048;
      for (int k2 = kend + lane * 4; k2 < 2048; k2 += 256) {
        f32x4 z = {0.f, 0.f, 0.f, 0.f};
        __builtin_nontemporal_store(z, (f32x4*)(rowp + k2));
      }
    }
    __syncthreads();   // B
    // ---------- cross-wave cacc sum + ctx store (p already normalized) ----------
    {
      int row = tid >> 4, c0 = (tid & 15) * 4;
      u16x4 o;
#pragma unroll
      for (int j = 0; j < 4; ++j) {
        float sum = cred[0][row][c0 + j] + cred[1][row][c0 + j] +
                    cred[2][row][c0 + j] + cred[3][row][c0 + j];
        o[j] = f2bf(sum);
      }
      *(u16x4*)&ctx[(long)(b * 2048 + q0 + row) * 512 + h * 64 + c0] = o;
    }
    __syncthreads();   // C (protects red_l/cred for next qsel)
  }
}

// ---- output projection: out = ctx @ Wo^T + bo (fp32 out) ----
__global__ __launch_bounds__(256) void k_oproj(
    const u16* __restrict__ ws0, const float* __restrict__ bo, float* __restrict__ out) {
  const int wv  = threadIdx.x >> 6;
  const int lane = threadIdx.x & 63;
  const int r16 = lane & 15, g8 = (lane >> 4) * 8, rq = (lane >> 4) * 4;
  const int t0 = blockIdx.x * 64 + wv * 16;
  const int e0 = blockIdx.y * 64;
  const u16* ctx = ws0 + OFF_CTX;
  const u16* wb  = ws0 + OFF_WO;
  f32x4 acc[4] = {};
  const u16* arow = ctx + (long)(t0 + r16) * 512 + g8;
  for (int f = 0; f < 512; f += 32) {
    bf16x8 a = *(const bf16x8*)(arow + f);
#pragma unroll
    for (int nt = 0; nt < 4; ++nt) {
      bf16x8 bfr = *(const bf16x8*)(wb + (long)(e0 + nt * 16 + r16) * 512 + f + g8);
      acc[nt] = mfma16(a, bfr, acc[nt]);
    }
  }
#pragma unroll
  for (int nt = 0; nt < 4; ++nt) {
    int e = e0 + nt * 16 + r16;
    float bb = bo[e];
#pragma unroll
    for (int r = 0; r < 4; ++r) {
      out[(long)(t0 + rq + r) * 512 + e] = acc[nt][r] + bb;
    }
  }
}

extern "C" void kernel_launch(void* const* d_in, const int* in_sizes, int n_in,
                              void* d_out, int out_size, void* d_ws, size_t ws_size,
                              hipStream_t stream) {
  if (ws_size < (size_t)WS_NEEDED_U16 * sizeof(u16)) return;  // fail clean, never fault
  const float* query = (const float*)d_in[0];
  const float* key   = (const float*)d_in[1];
  const float* value = (const float*)d_in[2];
  const int*   mask  = (const int*)d_in[3];
  const float* pbias = (const float*)d_in[4];
  const float* Wq = (const float*)d_in[5];
  const float* bq = (const float*)d_in[6];
  const float* Wk = (const float*)d_in[7];
  const float* bk = (const float*)d_in[8];
  const float* Wv = (const float*)d_in[9];
  const float* bv = (const float*)d_in[10];
  const float* Wo = (const float*)d_in[11];
  const float* bo = (const float*)d_in[12];
  float* out  = (float*)d_out;
  float* attn = out + 4194304L;
  u16* ws0 = (u16*)d_ws;

  k_cvt<<<13312, 256, 0, stream>>>(query, key, value, Wq, Wk, Wv, Wo, ws0);
  k_proj_qk<<<dim3(128, 8, 2), 256, 0, stream>>>(ws0, bq, bk);
  k_proj_v<<<dim3(8, 128), 256, 0, stream>>>(ws0, bv);
  k_attn<<<dim3(64, 32), 256, 0, stream>>>(ws0, pbias, mask, attn, (u16*)ws0 + OFF_CTX);
  k_oproj<<<dim3(128, 8), 256, 0, stream>>>(ws0, bo, out);
}

// Round 9
// 426.253 us; speedup vs baseline: 1.0082x; 1.0082x over previous
//
#include <hip/hip_runtime.h>

typedef __attribute__((ext_vector_type(8))) __bf16 bf16x8;
typedef __attribute__((ext_vector_type(4))) float f32x4;
typedef __attribute__((ext_vector_type(4))) unsigned short u16x4;
typedef unsigned short u16;

// ws layout (u16 element offsets)
#define OFF_QB   0L            // query bf16   [8192][512]
#define OFF_KB   4194304L      // key bf16
#define OFF_VB   8388608L      // value bf16
#define OFF_WQ   12582912L     // Wq bf16 [512][512]
#define OFF_WK   12845056L
#define OFF_WV   13107200L
#define OFF_WO   13369344L
#define OFF_QS   13631488L     // Q*(log2e/8)  [BH][2048][64] bf16
#define OFF_KS   17825792L     // K    [BH][2048][64]
#define OFF_VT   22020096L     // V^T  [BH][64][2048]
#define OFF_CTX  26214400L     // ctx  [8192][512]
#define WS_NEEDED_U16 30408704L

static __device__ __forceinline__ u16 f2bf(float f) {
  union { float f; unsigned u; } v; v.f = f;
  unsigned r = v.u + 0x7FFFu + ((v.u >> 16) & 1u);
  return (u16)(r >> 16);
}

static __device__ __forceinline__ f32x4 mfma16(bf16x8 a, bf16x8 b, f32x4 c) {
  return __builtin_amdgcn_mfma_f32_16x16x32_bf16(a, b, c, 0, 0, 0);
}

// ---- convert fp32 inputs/weights to bf16 in ws ----
__global__ __launch_bounds__(256) void k_cvt(
    const float* __restrict__ q, const float* __restrict__ k, const float* __restrict__ v,
    const float* __restrict__ wq, const float* __restrict__ wk, const float* __restrict__ wv,
    const float* __restrict__ wo, u16* __restrict__ ws0) {
  long i = ((long)blockIdx.x * 256 + threadIdx.x) * 4;
  const float* src; u16* dst; long off;
  if (i < 12582912L) {
    int which = (int)(i >> 22); off = i & 4194303L;
    src = which == 0 ? q : which == 1 ? k : v;
    dst = ws0 + (long)which * 4194304L;
  } else {
    long j = i - 12582912L;
    int which = (int)(j >> 18); off = j & 262143L;
    src = which == 0 ? wq : which == 1 ? wk : which == 2 ? wv : wo;
    dst = ws0 + 12582912L + (long)which * 262144L;
  }
  float4 f = *(const float4*)(src + off);
  u16x4 o; o.x = f2bf(f.x); o.y = f2bf(f.y); o.z = f2bf(f.z); o.w = f2bf(f.w);
  *(u16x4*)(dst + off) = o;
}

// ---- Q/K projections: C = X @ W^T + b, stored [BH][S][D]; Q scaled by log2e/8 ----
__global__ __launch_bounds__(256) void k_proj_qk(
    const u16* __restrict__ ws0, const float* __restrict__ bq, const float* __restrict__ bk) {
  const int wv  = threadIdx.x >> 6;
  const int lane = threadIdx.x & 63;
  const int r16 = lane & 15, g8 = (lane >> 4) * 8, rq = (lane >> 4) * 4;
  const int t0 = blockIdx.x * 64 + wv * 16;
  const int e0 = blockIdx.y * 64;
  const int z  = blockIdx.z;                 // 0=Q 1=K
  const u16* xb = ws0 + (z == 0 ? OFF_QB : OFF_KB);
  const u16* wb = ws0 + (z == 0 ? OFF_WQ : OFF_WK);
  const float* bias = (z == 0) ? bq : bk;
  u16* dst = (u16*)ws0 + (z == 0 ? OFF_QS : OFF_KS);
  const float scl = (z == 0) ? 0.125f * 1.4426950408889634f : 1.0f;

  f32x4 acc[4] = {};
  const u16* arow = xb + (long)(t0 + r16) * 512 + g8;
  for (int f = 0; f < 512; f += 32) {
    bf16x8 a = *(const bf16x8*)(arow + f);
#pragma unroll
    for (int nt = 0; nt < 4; ++nt) {
      bf16x8 bfr = *(const bf16x8*)(wb + (long)(e0 + nt * 16 + r16) * 512 + f + g8);
      acc[nt] = mfma16(a, bfr, acc[nt]);
    }
  }
#pragma unroll
  for (int nt = 0; nt < 4; ++nt) {
    int e = e0 + nt * 16 + r16;
    float bb = bias[e];
    int h = e >> 6, d = e & 63;
#pragma unroll
    for (int r = 0; r < 4; ++r) {
      int t = t0 + rq + r;
      int b = t >> 11, s = t & 2047;
      float val = (acc[nt][r] + bb) * scl;
      dst[((long)(b * 8 + h) * 2048 + s) * 64 + d] = f2bf(val);
    }
  }
}

// ---- V projection, transposed: C = Wv @ X^T (+bv per row), stored [BH][D][S] ----
__global__ __launch_bounds__(256) void k_proj_v(
    const u16* __restrict__ ws0, const float* __restrict__ bv) {
  const int wv  = threadIdx.x >> 6;
  const int lane = threadIdx.x & 63;
  const int r16 = lane & 15, g8 = (lane >> 4) * 8, rq = (lane >> 4) * 4;
  const int e0 = blockIdx.x * 64 + wv * 16;   // output channel rows
  const int t0 = blockIdx.y * 64;             // token cols
  const u16* xb = ws0 + OFF_VB;
  const u16* wb = ws0 + OFF_WV;
  u16* vt = (u16*)ws0 + OFF_VT;

  f32x4 acc[4] = {};
  const u16* arow = wb + (long)(e0 + r16) * 512 + g8;
  for (int f = 0; f < 512; f += 32) {
    bf16x8 a = *(const bf16x8*)(arow + f);
#pragma unroll
    for (int nt = 0; nt < 4; ++nt) {
      bf16x8 bfr = *(const bf16x8*)(xb + (long)(t0 + nt * 16 + r16) * 512 + f + g8);
      acc[nt] = mfma16(a, bfr, acc[nt]);
    }
  }
#pragma unroll
  for (int r = 0; r < 4; ++r) {
    int e = e0 + rq + r;
    float bb = bv[e];
    int h = e >> 6, d = e & 63;
#pragma unroll
    for (int nt = 0; nt < 4; ++nt) {
      int t = t0 + nt * 16 + r16;
      int b = t >> 11, s = t & 2047;
      vt[((long)((b * 8 + h) * 64 + d)) * 2048 + s] = f2bf(acc[nt][r] + bb);
    }
  }
}

// ---- fused attention v5: adjacent tile pairs, LDS-staged wide attn writes ----
// P1: partial l per wave (tiles ti = w mod 4) -> LDS reduce (barrier A).
// P2: wave owns ADJACENT pair (2w+8i, 2w+8i+1) = 16x32 block. Normalized fp32
// p staged to pw[16][36] -> PV (bf16 frags from pw) -> two f32x4 nontemporal
// stores per lane (128B-contiguous runs). Odd tail tile writes zeros.
// Barriers: A (l-reduce), B (cred stash -> ctx).
__global__ __launch_bounds__(256) void k_attn(
    const u16* __restrict__ ws0, const float* __restrict__ pos_bias,
    const int* __restrict__ mask, float* __restrict__ attn_out, u16* __restrict__ ctx) {
  __shared__ float red_l[4][16];
  __shared__ __align__(16) float cred[4][16][68];
  __shared__ __align__(16) float pw[4][16][36];

  const int tid = threadIdx.x;
  const int w = tid >> 6, lane = tid & 63;
  const int r16 = lane & 15, g = lane >> 4;
  const int g8 = g * 8, rq = g * 4;
  const int bh = blockIdx.y;                  // 0..31
  const int b = bh >> 3, h = bh & 7;
  const int pair = blockIdx.x;                // 0..63
  const u16* Qs = ws0 + OFF_QS + (long)bh * (2048 * 64);
  const u16* Ks = ws0 + OFF_KS + (long)bh * (2048 * 64);
  const u16* VT = ws0 + OFF_VT + (long)bh * (64 * 2048);
  const int* maskb = mask + b * 2048;
  const float NEG = -1e30f;
  const float L2E = 1.4426950408889634f;
  bool dg[4];                                  // causal kill on diagonal tile
#pragma unroll
  for (int r = 0; r < 4; ++r) dg[r] = (r16 > rq + r);

  for (int qsel = 0; qsel < 2; ++qsel) {
    const int qb = qsel ? (127 - pair) : pair;
    const int q0 = qb * 16;
    const int ntiles = qb + 1;
    bf16x8 qf0 = *(const bf16x8*)(Qs + (long)(q0 + r16) * 64 + g8);
    bf16x8 qf1 = *(const bf16x8*)(Qs + (long)(q0 + r16) * 64 + 32 + g8);
    const float* brow = pos_bias + ((long)h * 2048 + q0 + rq) * 2048;

    // ---------- P1: partial l over this wave's tiles ----------
    float l[4] = {0.f, 0.f, 0.f, 0.f};
    for (int ti = w; ti < ntiles; ti += 4) {
      int kcol = ti * 16 + r16;
      bf16x8 kf0 = *(const bf16x8*)(Ks + (long)kcol * 64 + g8);
      bf16x8 kf1 = *(const bf16x8*)(Ks + (long)kcol * 64 + 32 + g8);
      f32x4 s = {};
      s = mfma16(qf0, kf0, s);
      s = mfma16(qf1, kf1, s);
      bool mz = (maskb[kcol] == 0);
      bool edge = (ti == qb);                  // wave-uniform
#pragma unroll
      for (int r = 0; r < 4; ++r) {
        float sv = fmaf(brow[(long)r * 2048 + kcol], L2E, s[r]);
        if (mz || (edge && dg[r])) sv = NEG;
        l[r] += exp2f(sv);
      }
    }
#pragma unroll
    for (int r = 0; r < 4; ++r)
#pragma unroll
      for (int off = 1; off < 16; off <<= 1) l[r] += __shfl_xor(l[r], off);
    if (r16 == 0) {
#pragma unroll
      for (int r = 0; r < 4; ++r) red_l[w][rq + r] = l[r];
    }
    __syncthreads();   // A
    float cc[4];
#pragma unroll
    for (int r = 0; r < 4; ++r) {
      float ls = red_l[0][rq + r] + red_l[1][rq + r] + red_l[2][rq + r] + red_l[3][rq + r];
      cc[r] = -__log2f(ls);
    }

    // ---------- P2: adjacent pair -> pw stage -> PV + wide attn write ----------
    f32x4 cacc[4] = {};
    float* arow = attn_out + ((long)bh * 2048 + q0) * 2048;
    for (int ta = 2 * w; ta < ntiles; ta += 8) {
      const int tb = ta + 1;
      const bool have1 = (tb < ntiles);
      {
        int kcol = ta * 16 + r16;
        bf16x8 kf0 = *(const bf16x8*)(Ks + (long)kcol * 64 + g8);
        bf16x8 kf1 = *(const bf16x8*)(Ks + (long)kcol * 64 + 32 + g8);
        f32x4 s = {};
        s = mfma16(qf0, kf0, s);
        s = mfma16(qf1, kf1, s);
        bool mz = (maskb[kcol] == 0);
        bool edge = (ta == qb);
#pragma unroll
        for (int r = 0; r < 4; ++r) {
          float sv = fmaf(brow[(long)r * 2048 + kcol], L2E, s[r]);
          if (mz || (edge && dg[r])) sv = NEG;
          pw[w][rq + r][r16] = exp2f(sv + cc[r]);
        }
      }
      if (have1) {
        int kcol = tb * 16 + r16;
        bf16x8 kf0 = *(const bf16x8*)(Ks + (long)kcol * 64 + g8);
        bf16x8 kf1 = *(const bf16x8*)(Ks + (long)kcol * 64 + 32 + g8);
        f32x4 s = {};
        s = mfma16(qf0, kf0, s);
        s = mfma16(qf1, kf1, s);
        bool mz = (maskb[kcol] == 0);
        bool edge = (tb == qb);
#pragma unroll
        for (int r = 0; r < 4; ++r) {
          float sv = fmaf(brow[(long)r * 2048 + kcol], L2E, s[r]);
          if (mz || (edge && dg[r])) sv = NEG;
          pw[w][rq + r][16 + r16] = exp2f(sv + cc[r]);
        }
      } else {
#pragma unroll
        for (int r = 0; r < 4; ++r) pw[w][rq + r][16 + r16] = 0.0f;
      }
      // PV: bf16 A-fragment built from pw (wave-local, compiler orders LDS)
      {
        f32x4 a0 = *(const f32x4*)&pw[w][r16][g8];
        f32x4 a1 = *(const f32x4*)&pw[w][r16][g8 + 4];
        union { bf16x8 v; u16 s[8]; } pu;
#pragma unroll
        for (int j = 0; j < 4; ++j) { pu.s[j] = f2bf(a0[j]); pu.s[4 + j] = f2bf(a1[j]); }
        int tsel = (g < 2) ? ta : (have1 ? tb : ta);
        const u16* vcol = VT + tsel * 16 + (g8 & 15);
#pragma unroll
        for (int dt = 0; dt < 4; ++dt) {
          bf16x8 vf = *(const bf16x8*)(vcol + (long)(dt * 16 + r16) * 2048);
          cacc[dt] = mfma16(pu.v, vf, cacc[dt]);
        }
      }
      // wide attn write: wave's 16x32 block, f32x4 x2 per lane
      {
        int row = lane >> 2, cs = (lane & 3) * 8;
        const float* src = &pw[w][row][cs];
        f32x4 v0 = *(const f32x4*)src;
        f32x4 v1 = *(const f32x4*)(src + 4);
        float* drow = arow + (long)row * 2048 + ta * 16 + cs;
        __builtin_nontemporal_store(v0, (f32x4*)drow);
        __builtin_nontemporal_store(v1, (f32x4*)(drow + 4));
      }
    }
    // stash partial cacc
#pragma unroll
    for (int dt = 0; dt < 4; ++dt)
#pragma unroll
      for (int r = 0; r < 4; ++r)
        cred[w][rq + r][dt * 16 + r16] = cacc[dt][r];

    // zero tail [tail_start, 2048), rows split across waves
    const int tail_start = ((ntiles + 1) & ~1) * 16;
    for (int rr = w; rr < 16; rr += 4) {
      float* rowp = arow + (long)rr * 2048;
      for (int k2 = tail_start + lane * 4; k2 < 2048; k2 += 256) {
        f32x4 z = {0.f, 0.f, 0.f, 0.f};
        __builtin_nontemporal_store(z, (f32x4*)(rowp + k2));
      }
    }
    __syncthreads();   // B
    // ---------- cross-wave cacc sum + ctx store (p already normalized) ----------
    {
      int row = tid >> 4, c0 = (tid & 15) * 4;
      u16x4 o;
#pragma unroll
      for (int j = 0; j < 4; ++j) {
        float sum = cred[0][row][c0 + j] + cred[1][row][c0 + j] +
                    cred[2][row][c0 + j] + cred[3][row][c0 + j];
        o[j] = f2bf(sum);
      }
      *(u16x4*)&ctx[(long)(b * 2048 + q0 + row) * 512 + h * 64 + c0] = o;
    }
  }
}

// ---- output projection: out = ctx @ Wo^T + bo (fp32 out) ----
__global__ __launch_bounds__(256) void k_oproj(
    const u16* __restrict__ ws0, const float* __restrict__ bo, float* __restrict__ out) {
  const int wv  = threadIdx.x >> 6;
  const int lane = threadIdx.x & 63;
  const int r16 = lane & 15, g8 = (lane >> 4) * 8, rq = (lane >> 4) * 4;
  const int t0 = blockIdx.x * 64 + wv * 16;
  const int e0 = blockIdx.y * 64;
  const u16* ctx = ws0 + OFF_CTX;
  const u16* wb  = ws0 + OFF_WO;
  f32x4 acc[4] = {};
  const u16* arow = ctx + (long)(t0 + r16) * 512 + g8;
  for (int f = 0; f < 512; f += 32) {
    bf16x8 a = *(const bf16x8*)(arow + f);
#pragma unroll
    for (int nt = 0; nt < 4; ++nt) {
      bf16x8 bfr = *(const bf16x8*)(wb + (long)(e0 + nt * 16 + r16) * 512 + f + g8);
      acc[nt] = mfma16(a, bfr, acc[nt]);
    }
  }
#pragma unroll
  for (int nt = 0; nt < 4; ++nt) {
    int e = e0 + nt * 16 + r16;
    float bb = bo[e];
#pragma unroll
    for (int r = 0; r < 4; ++r) {
      out[(long)(t0 + rq + r) * 512 + e] = acc[nt][r] + bb;
    }
  }
}

extern "C" void kernel_launch(void* const* d_in, const int* in_sizes, int n_in,
                              void* d_out, int out_size, void* d_ws, size_t ws_size,
                              hipStream_t stream) {
  if (ws_size < (size_t)WS_NEEDED_U16 * sizeof(u16)) return;  // fail clean, never fault
  const float* query = (const float*)d_in[0];
  const float* key   = (const float*)d_in[1];
  const float* value = (const float*)d_in[2];
  const int*   mask  = (const int*)d_in[3];
  const float* pbias = (const float*)d_in[4];
  const float* Wq = (const float*)d_in[5];
  const float* bq = (const float*)d_in[6];
  const float* Wk = (const float*)d_in[7];
  const float* bk = (const float*)d_in[8];
  const float* Wv = (const float*)d_in[9];
  const float* bv = (const float*)d_in[10];
  const float* Wo = (const float*)d_in[11];
  const float* bo = (const float*)d_in[12];
  float* out  = (float*)d_out;
  float* attn = out + 4194304L;
  u16* ws0 = (u16*)d_ws;

  k_cvt<<<13312, 256, 0, stream>>>(query, key, value, Wq, Wk, Wv, Wo, ws0);
  k_proj_qk<<<dim3(128, 8, 2), 256, 0, stream>>>(ws0, bq, bk);
  k_proj_v<<<dim3(8, 128), 256, 0, stream>>>(ws0, bv);
  k_attn<<<dim3(64, 32), 256, 0, stream>>>(ws0, pbias, mask, attn, (u16*)ws0 + OFF_CTX);
  k_oproj<<<dim3(128, 8), 256, 0, stream>>>(ws0, bo, out);
}